// Round 1
// baseline (76.131 us; speedup 1.0000x reference)
//
#include <hip/hip_runtime.h>
#include <math.h>

#define BLOCK 256
#define WPB 4          // waves per block
#define NGRID 1000

__global__ __launch_bounds__(BLOCK) void ph_kernel(
    const float* __restrict__ x,
    const float* __restrict__ W1, const float* __restrict__ b1,
    const float* __restrict__ W2, const float* __restrict__ b2,
    const float* __restrict__ W3, const float* __restrict__ b3,
    const float* __restrict__ W4, const float* __restrict__ b4,
    const float* __restrict__ kin,
    float* __restrict__ out, int B)
{
    __shared__ float sW1[5*64];
    __shared__ float sB1[64];
    __shared__ float sW2[64*64];
    __shared__ float sB2[64];
    __shared__ float sW3[64*64];
    __shared__ float sB3[64];
    __shared__ float sW4[64*6];
    __shared__ float sB4[8];
    __shared__ float sTF[3*NGRID];
    __shared__ float sH[WPB][64];
    __shared__ float sLat[WPB][8];

    const int tid = threadIdx.x;

    // ---- stage weights into LDS ----
    for (int i = tid; i < 5*64;  i += BLOCK) sW1[i] = W1[i];
    for (int i = tid; i < 64*64; i += BLOCK) sW2[i] = W2[i];
    for (int i = tid; i < 64*64; i += BLOCK) sW3[i] = W3[i];
    for (int i = tid; i < 64*6;  i += BLOCK) sW4[i] = W4[i];
    if (tid < 64) { sB1[tid] = b1[tid]; sB2[tid] = b2[tid]; sB3[tid] = b3[tid]; }
    if (tid < 6)  { sB4[tid] = b4[tid]; }

    // ---- Tafel table (row-independent): tafel[s][v] ----
    const float a0 = kin[3], a1 = kin[4], a2 = kin[5];
    const float stepV = 1.25f / 999.0f;
    for (int i = tid; i < 3*NGRID; i += BLOCK) {
        int s = i / NGRID;
        int v = i - s*NGRID;
        float alpha = (s == 0) ? a0 : ((s == 1) ? a1 : a2);
        float e0    = (s == 0) ? -0.11f : ((s == 1) ? 0.08f : 0.0f);
        float V   = -1.25f + stepV * (float)v;
        float eta = V - e0;
        // reference order: ((-alpha)*F)*eta / RT
        sTF[i] = expf(((-alpha) * 96485.33f) * eta / 2478.8191f);
    }
    __syncthreads();

    const int lane = tid & 63;
    const int widx = tid >> 6;
    const int nw   = gridDim.x * WPB;
    const int w    = blockIdx.x * WPB + widx;
    const int nIter = (B + nw - 1) / nw;

    const float i00 = kin[0], i01 = kin[1], i02 = kin[2];

    for (int it = 0; it < nIter; ++it) {
        const int b   = w + it * nw;
        const bool act = (b < B);
        const int bb  = act ? b : 0;

        // ---- MLP: lane j owns hidden unit j ----
        float h;
        {
            float acc = sB1[lane];
            #pragma unroll
            for (int i = 0; i < 5; ++i)
                acc = fmaf(x[bb*5 + i], sW1[i*64 + lane], acc);
            h = fmaxf(acc, 0.0f);
        }
        __syncthreads();
        sH[widx][lane] = h;
        __syncthreads();
        {
            float acc = sB2[lane];
            #pragma unroll 8
            for (int i = 0; i < 64; ++i)
                acc = fmaf(sH[widx][i], sW2[i*64 + lane], acc);
            h = fmaxf(acc, 0.0f);
        }
        __syncthreads();
        sH[widx][lane] = h;
        __syncthreads();
        {
            float acc = sB3[lane];
            #pragma unroll 8
            for (int i = 0; i < 64; ++i)
                acc = fmaf(sH[widx][i], sW3[i*64 + lane], acc);
            h = fmaxf(acc, 0.0f);
        }
        __syncthreads();
        sH[widx][lane] = h;
        __syncthreads();
        if (lane < 6) {
            float acc = sB4[lane];
            #pragma unroll 8
            for (int i = 0; i < 64; ++i)
                acc = fmaf(sH[widx][i], sW4[i*6 + lane], acc);
            sLat[widx][lane] = acc;
        }
        __syncthreads();

        const float lat0 = sLat[widx][0];
        const float lat1 = sLat[widx][1];
        const float lat2 = sLat[widx][2];
        const float lat3 = sLat[widx][3];
        const float lat4 = sLat[widx][4];
        const float lat5 = sLat[widx][5];

        // ---- physics scalars (all lanes redundantly) ----
        const float r    = 4e-8f * expf(lat0);
        const float epsv = 1.0f / (1.0f + expf(-lat1));
        const float zlt  = x[bb*5 + 3];
        const float Lf   = zlt / (1.0f - epsv);
        const float Kdl  = expf(lat2);
        const float z0 = 2.0f*lat3, z1 = 2.0f*lat4, z2 = 2.0f*lat5;
        const float m  = fmaxf(z0, fmaxf(z1, z2));
        const float p0 = expf(z0 - m), p1 = expf(z1 - m), p2 = expf(z2 - m);
        const float ps = p0 + p1 + p2;
        const float th0 = p0/ps, th1 = p1/ps, th2 = p2/ps;
        const float gdl   = (Kdl * 1.91e-9f) * powf(epsv, 1.5f) / r;
        const float asurf = (3.0f * (1.0f - epsv)) * Lf / r;
        const float c0 = (i00*th0)*asurf, c1 = (i01*th1)*asurf, c2 = (i02*th2)*asurf;
        const float il0  = (((2.0f*96485.33f)*34.0f)*gdl)*0.1f;
        const float il1  = (((12.0f*96485.33f)*34.0f)*gdl)*0.1f;
        const float invl0 = 1.0f/il0, invl1 = 1.0f/il1;

        // ---- scan 1000 V points across 64 lanes ----
        float bd = __builtin_inff();
        int bidx = 0;
        #pragma unroll 4
        for (int k = 0; k < 16; ++k) {
            int v = lane + (k << 6);
            if (v < NGRID) {
                float t0 = sTF[v], t1 = sTF[NGRID + v], t2 = sTF[2*NGRID + v];
                float ie0 = 1.0f / (1.0f/(c0*t0) + invl0);
                float ie1 = 1.0f / (1.0f/(c1*t1) + invl1);
                float ie2 = 1.0f / (1.0f/(c2*t2));   // i_lim[2] = inf
                float tot = ie0 + ie1 + ie2;
                float d = fabsf(tot - 200.0f);
                if (d < bd) { bd = d; bidx = v; }
            }
        }
        // first-min-preserving butterfly reduction
        #pragma unroll
        for (int off = 32; off; off >>= 1) {
            float od = __shfl_xor(bd, off, 64);
            int   oi = __shfl_xor(bidx, off, 64);
            if (od < bd || (od == bd && oi < bidx)) { bd = od; bidx = oi; }
        }

        // ---- select + FE ----
        float t0 = sTF[bidx], t1 = sTF[NGRID + bidx], t2 = sTF[2*NGRID + bidx];
        float ie0 = 1.0f / (1.0f/(c0*t0) + invl0);
        float ie1 = 1.0f / (1.0f/(c1*t1) + invl1);
        float ie2 = 1.0f / (1.0f/(c2*t2));
        float itsel = ie0 + ie1 + ie2;
        if (act && lane < 2) {
            out[bb*2 + lane] = (lane == 0) ? (ie1/itsel) : (ie0/itsel);
        }
    }
}

extern "C" void kernel_launch(void* const* d_in, const int* in_sizes, int n_in,
                              void* d_out, int out_size, void* d_ws, size_t ws_size,
                              hipStream_t stream) {
    const float* x   = (const float*)d_in[0];
    const float* W1  = (const float*)d_in[1];
    const float* b1  = (const float*)d_in[2];
    const float* W2  = (const float*)d_in[3];
    const float* b2  = (const float*)d_in[4];
    const float* W3  = (const float*)d_in[5];
    const float* b3  = (const float*)d_in[6];
    const float* W4  = (const float*)d_in[7];
    const float* b4  = (const float*)d_in[8];
    const float* kin = (const float*)d_in[9];
    float* out = (float*)d_out;
    const int B = in_sizes[0] / 5;

    const int grid = 1024;
    ph_kernel<<<grid, BLOCK, 0, stream>>>(x, W1, b1, W2, b2, W3, b3, W4, b4, kin, out, B);
}

// Round 2
// 38.001 us; speedup vs baseline: 2.0034x; 2.0034x over previous
//
#include <hip/hip_runtime.h>
#include <math.h>

#define BLOCK 512
#define WPB 8          // waves per block
#define NGRID 1000
#define HPAD 68        // 272B row stride: 16B-aligned, bank-conflict-free for layer4

// Dense 64->64 layer for 4 rows per wave. Lane j owns output unit j.
// Weights pre-transposed+swizzled in LDS: row j holds column j of W,
// 16B granule g stored at position (g ^ (j&7)) -> conflict-free b128 reads.
// In-place h update is safe: wave64 lockstep + per-thread may-alias ordering
// means all lanes' reads of row r retire before any lane's write to row r.
__device__ __forceinline__ void dense64(const float* __restrict__ wt,
                                        const float* __restrict__ bias,
                                        float (*h)[HPAD], int j)
{
    const int swz = j & 7;
    const float* wrow = wt + (j << 6);
    float ac0 = bias[j];
    float ac1 = ac0, ac2 = ac0, ac3 = ac0;
    #pragma unroll
    for (int i4 = 0; i4 < 16; ++i4) {
        const float4 wv = *(const float4*)(wrow + ((i4 ^ swz) << 2));
        const float4 h0 = *(const float4*)(&h[0][i4 << 2]);
        const float4 h1 = *(const float4*)(&h[1][i4 << 2]);
        const float4 h2 = *(const float4*)(&h[2][i4 << 2]);
        const float4 h3 = *(const float4*)(&h[3][i4 << 2]);
        ac0 = fmaf(h0.x, wv.x, ac0); ac0 = fmaf(h0.y, wv.y, ac0);
        ac0 = fmaf(h0.z, wv.z, ac0); ac0 = fmaf(h0.w, wv.w, ac0);
        ac1 = fmaf(h1.x, wv.x, ac1); ac1 = fmaf(h1.y, wv.y, ac1);
        ac1 = fmaf(h1.z, wv.z, ac1); ac1 = fmaf(h1.w, wv.w, ac1);
        ac2 = fmaf(h2.x, wv.x, ac2); ac2 = fmaf(h2.y, wv.y, ac2);
        ac2 = fmaf(h2.z, wv.z, ac2); ac2 = fmaf(h2.w, wv.w, ac2);
        ac3 = fmaf(h3.x, wv.x, ac3); ac3 = fmaf(h3.y, wv.y, ac3);
        ac3 = fmaf(h3.z, wv.z, ac3); ac3 = fmaf(h3.w, wv.w, ac3);
    }
    h[0][j] = fmaxf(ac0, 0.0f);
    h[1][j] = fmaxf(ac1, 0.0f);
    h[2][j] = fmaxf(ac2, 0.0f);
    h[3][j] = fmaxf(ac3, 0.0f);
}

__global__ __launch_bounds__(BLOCK) void ph_kernel(
    const float* __restrict__ x,
    const float* __restrict__ W1, const float* __restrict__ b1,
    const float* __restrict__ W2, const float* __restrict__ b2,
    const float* __restrict__ W3, const float* __restrict__ b3,
    const float* __restrict__ W4, const float* __restrict__ b4,
    const float* __restrict__ kin,
    float* __restrict__ out, int B)
{
    __shared__ __attribute__((aligned(16))) float sW2t[64*64];
    __shared__ __attribute__((aligned(16))) float sW3t[64*64];
    __shared__ __attribute__((aligned(16))) float sH[WPB][4][HPAD];
    __shared__ float sW1[5*64];
    __shared__ float sW4[64*6];
    __shared__ float sB1[64], sB2[64], sB3[64], sB4[8];
    __shared__ float sTF[3*NGRID];
    __shared__ float sLat[WPB][4][8];

    const int tid = threadIdx.x;

    // ---- stage weights (W2/W3 transposed + XOR-swizzled 16B granules) ----
    for (int l = tid; l < 5*64; l += BLOCK) sW1[l] = W1[l];
    for (int l = tid; l < 64*6; l += BLOCK) sW4[l] = W4[l];
    for (int l = tid; l < 64*64; l += BLOCK) {
        const int i = l >> 6, j = l & 63;
        const int dst = (j << 6) + ((((i >> 2) ^ (j & 7)) << 2) | (i & 3));
        sW2t[dst] = W2[l];
        sW3t[dst] = W3[l];
    }
    if (tid < 64) { sB1[tid] = b1[tid]; sB2[tid] = b2[tid]; sB3[tid] = b3[tid]; }
    if (tid < 8)  sB4[tid] = (tid < 6) ? b4[tid] : 0.0f;

    // ---- Tafel table (row-independent): tafel[s][v], exact ref op order ----
    const float a0k = kin[3], a1k = kin[4], a2k = kin[5];
    const float stepV = 1.25f / 999.0f;
    for (int i = tid; i < 3*NGRID; i += BLOCK) {
        const int s = i / NGRID;
        const int v = i - s*NGRID;
        const float alpha = (s == 0) ? a0k : ((s == 1) ? a1k : a2k);
        const float e0    = (s == 0) ? -0.11f : ((s == 1) ? 0.08f : 0.0f);
        const float V   = -1.25f + stepV * (float)v;
        const float eta = V - e0;
        sTF[i] = expf(((-alpha) * 96485.33f) * eta / 2478.8191f);
    }
    __syncthreads();   // the ONLY block-wide barrier

    const int lane = tid & 63;
    const int widx = tid >> 6;
    const int nw   = gridDim.x * WPB;
    const int w    = blockIdx.x * WPB + widx;
    const float i00 = kin[0], i01 = kin[1], i02 = kin[2];

    float (*h)[HPAD] = sH[widx];
    const int j = lane;

    for (int row0 = w*4; row0 < B; row0 += nw*4) {
        // ---- layer 1: 5 -> 64 (x reads are wave-uniform -> scalar loads) ----
        #pragma unroll
        for (int r = 0; r < 4; ++r) {
            const int row = (row0 + r < B) ? (row0 + r) : (B - 1);
            float acc = sB1[j];
            #pragma unroll
            for (int i = 0; i < 5; ++i)
                acc = fmaf(x[row*5 + i], sW1[(i << 6) + j], acc);
            h[r][j] = fmaxf(acc, 0.0f);
        }

        // ---- layers 2,3: 64 -> 64 ----
        dense64(sW2t, sB2, h, j);
        dense64(sW3t, sB3, h, j);

        // ---- layer 4: 64 -> 6, lanes 0..23 = (r = lane&3, u = lane>>2) ----
        if (lane < 24) {
            const int r = lane & 3, u = lane >> 2;
            float acc = sB4[u];
            #pragma unroll 8
            for (int i = 0; i < 64; ++i)
                acc = fmaf(h[r][i], sW4[i*6 + u], acc);
            sLat[widx][r][u] = acc;
        }

        // ---- physics + two-level scan, one row at a time ----
        #pragma unroll 1
        for (int r = 0; r < 4; ++r) {
            const int row = row0 + r;
            if (row >= B) break;

            const float lat0 = sLat[widx][r][0];
            const float lat1 = sLat[widx][r][1];
            const float lat2 = sLat[widx][r][2];
            const float lat3 = sLat[widx][r][3];
            const float lat4 = sLat[widx][r][4];
            const float lat5 = sLat[widx][r][5];

            const float rr   = 4e-8f * expf(lat0);
            const float epsv = 1.0f / (1.0f + expf(-lat1));
            const float zlt  = x[row*5 + 3];
            const float Lf   = zlt / (1.0f - epsv);
            const float Kdl  = expf(lat2);
            const float z0 = 2.0f*lat3, z1 = 2.0f*lat4, z2 = 2.0f*lat5;
            const float mz = fmaxf(z0, fmaxf(z1, z2));
            const float p0 = expf(z0 - mz), p1 = expf(z1 - mz), p2 = expf(z2 - mz);
            const float ps = p0 + p1 + p2;
            const float th0 = p0/ps, th1 = p1/ps, th2 = p2/ps;
            const float gdl   = (Kdl * 1.91e-9f) * powf(epsv, 1.5f) / rr;
            const float asurf = (3.0f * (1.0f - epsv)) * Lf / rr;
            const float c0 = (i00*th0)*asurf, c1 = (i01*th1)*asurf, c2 = (i02*th2)*asurf;
            const float il0  = (((2.0f*96485.33f)*34.0f)*gdl)*0.1f;
            const float il1  = (((12.0f*96485.33f)*34.0f)*gdl)*0.1f;
            const float invl0 = 1.0f/il0, invl1 = 1.0f/il1;

            // exact per-point evaluation (identical op order to full scan)
            auto evaltot = [&](int v) -> float {
                const float t0 = sTF[v], t1 = sTF[NGRID + v], t2 = sTF[2*NGRID + v];
                const float ie0 = 1.0f / (1.0f/(c0*t0) + invl0);
                const float ie1 = 1.0f / (1.0f/(c1*t1) + invl1);
                const float ie2 = 1.0f / (1.0f/(c2*t2));   // i_lim[2] = inf
                return ie0 + ie1 + ie2;
            };

            // coarse: lane k samples v = 16k (clamped); i_tot is monotone
            // non-increasing in v, so the argmin of |i_tot-200| is adjacent
            // to the 200-crossing, bracketed by the last coarse point >= 200.
            const int vc = (lane << 4) < NGRID-1 ? (lane << 4) : NGRID-1;
            const float totc = evaltot(vc);
            float bd = fabsf(totc - 200.0f);
            int bidx = vc;

            const unsigned long long mge = __ballot(totc >= 200.0f);
            const int kstar = (mge == 0ull) ? 0 : (63 - __builtin_clzll(mge));
            int base = (kstar << 4) - 16;          // one segment of margin
            if (base < 0) base = 0;

            // fine: 33-point exact window around the crossing
            if (lane <= 32) {
                const int vf = (base + lane < NGRID-1) ? (base + lane) : NGRID-1;
                const float totf = evaltot(vf);
                const float df = fabsf(totf - 200.0f);
                if (df < bd || (df == bd && vf < bidx)) { bd = df; bidx = vf; }
            }

            // lexicographic (d, idx) butterfly -> first-occurrence argmin
            #pragma unroll
            for (int off = 32; off; off >>= 1) {
                const float od = __shfl_xor(bd, off, 64);
                const int   oi = __shfl_xor(bidx, off, 64);
                if (od < bd || (od == bd && oi < bidx)) { bd = od; bidx = oi; }
            }

            // ---- select + FE (exact, same as reference) ----
            const float t0 = sTF[bidx], t1 = sTF[NGRID + bidx], t2 = sTF[2*NGRID + bidx];
            const float ie0 = 1.0f / (1.0f/(c0*t0) + invl0);
            const float ie1 = 1.0f / (1.0f/(c1*t1) + invl1);
            const float ie2 = 1.0f / (1.0f/(c2*t2));
            const float itsel = ie0 + ie1 + ie2;
            if (lane < 2) {
                out[row*2 + lane] = (lane == 0) ? (ie1/itsel) : (ie0/itsel);
            }
        }
    }
}

extern "C" void kernel_launch(void* const* d_in, const int* in_sizes, int n_in,
                              void* d_out, int out_size, void* d_ws, size_t ws_size,
                              hipStream_t stream) {
    const float* x   = (const float*)d_in[0];
    const float* W1  = (const float*)d_in[1];
    const float* b1  = (const float*)d_in[2];
    const float* W2  = (const float*)d_in[3];
    const float* b2  = (const float*)d_in[4];
    const float* W3  = (const float*)d_in[5];
    const float* b3  = (const float*)d_in[6];
    const float* W4  = (const float*)d_in[7];
    const float* b4  = (const float*)d_in[8];
    const float* kin = (const float*)d_in[9];
    float* out = (float*)d_out;
    const int B = in_sizes[0] / 5;

    // 32 rows per block (8 waves x 4 rows): B=16384 -> 512 blocks
    // = exactly 2 resident blocks per CU (58 KB LDS), no dispatch tail.
    const int grid = (B + WPB*4 - 1) / (WPB*4);
    ph_kernel<<<grid, BLOCK, 0, stream>>>(x, W1, b1, W2, b2, W3, b3, W4, b4, kin, out, B);
}